// Round 4
// baseline (1091.456 us; speedup 1.0000x reference)
//
#include <hip/hip_runtime.h>
#include <hip/hip_cooperative_groups.h>
#include <hip/hip_bf16.h>
#include <hip/hip_fp16.h>

// ---------------------------------------------------------------------------
// GNN: h = relu(GCN(x)); h = relu(GAT(h)); h = relu(GCN(h)); h = relu(GAT(h));
//      z = h @ Wo + bo.  Outputs: [h (N*128), z (N*64)] fp32.
// R12: cooperative mega-kernel. R9-R11 showed ~280-310us of kernel time inside
//     378-401us totals -> ~70-100us of dispatch gaps/tails across 15-23
//     launches. Main loop (5 GEMMs + 4 aggs) is now ONE cooperative kernel
//     with grid.sync() between 9 phases. GEMM B-fragments are read directly
//     from L2-resident Wt (no LDS, no syncthreads) so the kernel has zero LDS
//     and runs 4 blocks/CU @ <=128 VGPR (launch_bounds(256,4)). Sort (R11)
//     REVERTED - it regressed 19us and bought nothing. Agg/alpha math is the
//     proven R8/R9 fused structure, bit-identical. Fallback: if cooperative
//     launch is unavailable, the same phases run as 9 discrete dispatches.
// ---------------------------------------------------------------------------

namespace cg = cooperative_groups;

#define WAVE 64
#define BK 256        // nodes per bucket
#define CHUNK 4096    // edges per k_bscatter block

typedef _Float16 f16x8 __attribute__((ext_vector_type(8)));
typedef float f32x4 __attribute__((ext_vector_type(4)));

__global__ void k_zero_i32(int* __restrict__ p, int n) {
    int i = blockIdx.x * 256 + threadIdx.x;
    if (i < n) p[i] = 0;
}

// ------------------------------ graph build --------------------------------
// edge e in [0,E): (s,d) = (ei[e], ei[E+e]); e in [E,Et): self-loop (e-E,e-E)

__global__ __launch_bounds__(256) void k_bhist(
    const int* __restrict__ ei, int* __restrict__ bcnt,
    int E, int Et, int nbuck) {
    __shared__ int hist[256];
    int tid = threadIdx.x;
    if (tid < nbuck) hist[tid] = 0;
    __syncthreads();
    for (int e = blockIdx.x * 256 + tid; e < Et; e += gridDim.x * 256) {
        int d = (e < E) ? ei[E + e] : (e - E);
        atomicAdd(&hist[d >> 8], 1);
    }
    __syncthreads();
    if (tid < nbuck && hist[tid] > 0) atomicAdd(&bcnt[tid], hist[tid]);
}

__global__ void k_bscan(const int* __restrict__ bcnt, int* __restrict__ bbase,
                        int* __restrict__ bcur, int nbuck) {
    __shared__ int tmp[256];
    int tid = threadIdx.x;
    int v = (tid < nbuck) ? bcnt[tid] : 0;
    tmp[tid] = v;
    __syncthreads();
    for (int off = 1; off < 256; off <<= 1) {
        int t = (tid >= off) ? tmp[tid - off] : 0;
        __syncthreads();
        tmp[tid] += t;
        __syncthreads();
    }
    if (tid < nbuck) {
        int excl = tmp[tid] - v;
        bbase[tid] = excl;
        bcur[tid] = excl;
        if (tid == nbuck - 1) bbase[nbuck] = tmp[tid];
    }
}

__global__ __launch_bounds__(256) void k_bscatter(
    const int* __restrict__ ei, int* __restrict__ bcur,
    int2* __restrict__ ebuf, int E, int Et, int nbuck) {
    __shared__ int hist[256];
    __shared__ int base[256];
    __shared__ int off[256];
    constexpr int PT = CHUNK / 256;   // 16 edges per thread
    int tid = threadIdx.x;
    int cb = blockIdx.x * CHUNK;
    if (tid < nbuck) { hist[tid] = 0; off[tid] = 0; }
    __syncthreads();

    int sv[PT], dv[PT];
#pragma unroll
    for (int i = 0; i < PT; ++i) {
        int e = cb + i * 256 + tid;
        int s = 0, d = -1;
        if (e < Et) {
            if (e < E) { s = ei[e]; d = ei[E + e]; }
            else       { s = d = e - E; }
            atomicAdd(&hist[d >> 8], 1);
        }
        sv[i] = s; dv[i] = d;
    }
    __syncthreads();
    if (tid < nbuck && hist[tid] > 0)
        base[tid] = atomicAdd(&bcur[tid], hist[tid]);
    __syncthreads();
#pragma unroll
    for (int i = 0; i < PT; ++i) {
        if (dv[i] >= 0) {
            int b = dv[i] >> 8;
            int pos = base[b] + atomicAdd(&off[b], 1);
            ebuf[pos] = make_int2(sv[i], dv[i]);
        }
    }
}

__global__ __launch_bounds__(256) void k_csr(
    const int2* __restrict__ ebuf, const int* __restrict__ bbase,
    int* __restrict__ rowp, float* __restrict__ inv, int* __restrict__ esrc,
    int Nn, int Et) {
    __shared__ int hist[256];
    __shared__ int scan[256];
    __shared__ int cur[256];
    int tid = threadIdx.x;
    int b = blockIdx.x;
    int bb = bbase[b], cnt = bbase[b + 1] - bb;
    hist[tid] = 0;
    __syncthreads();
    for (int t = tid; t < cnt; t += 256)
        atomicAdd(&hist[ebuf[bb + t].y & 255], 1);
    __syncthreads();
    int v = hist[tid];
    scan[tid] = v;
    __syncthreads();
    for (int o = 1; o < 256; o <<= 1) {
        int t = (tid >= o) ? scan[tid - o] : 0;
        __syncthreads();
        scan[tid] += t;
        __syncthreads();
    }
    int excl = scan[tid] - v;
    int node = b * BK + tid;
    if (node < Nn) {
        rowp[node] = bb + excl;
        inv[node] = rsqrtf((float)v);
    }
    cur[tid] = excl;
    if (b == 0 && tid == 0) rowp[Nn] = Et;
    __syncthreads();
    for (int t = tid; t < cnt; t += 256) {
        int2 e = ebuf[bb + t];
        int pos = bb + atomicAdd(&cur[e.y & 255], 1);
        esrc[pos] = e.x;
    }
}

// -------------------- weight convert (fp32 -> fp16, fragment-major) --------
// Wt layout: [0]W1 [16384]Wg1 [32768]W2 [49152]Wg2 [65536]Wo
// Within each weight, B-fragments stored contiguously:
//   elem ((nt*4 + ks)*64 + lane)*8 + j  =  W[k][n]
//   with n = nt*16 + (lane&15), k = ks*32 + (lane>>4)*8 + j.

__global__ void k_wcvt(const float* __restrict__ W1, const float* __restrict__ Wg1,
                       const float* __restrict__ W2, const float* __restrict__ Wg2,
                       const float* __restrict__ Wo, __half* __restrict__ Wt) {
    int i = blockIdx.x * 256 + threadIdx.x;   // 73728 total
    if (i < 65536) {
        int w = i >> 14;
        int j = i & 16383;
        int nt = j >> 11, ks = (j >> 9) & 3, lane = (j >> 3) & 63, jj = j & 7;
        int n = nt * 16 + (lane & 15);
        int k = ks * 32 + (lane >> 4) * 8 + jj;
        const float* W = (w == 0) ? W1 : (w == 1) ? Wg1 : (w == 2) ? W2 : Wg2;
        Wt[i] = __float2half(W[k * 128 + n]);
    } else if (i < 73728) {
        int j = i - 65536;                    // 8192: Wo is 128x64 -> NT=4
        int nt = j >> 11, ks = (j >> 9) & 3, lane = (j >> 3) & 63, jj = j & 7;
        int n = nt * 16 + (lane & 15);
        int k = ks * 32 + (lane >> 4) * 8 + jj;
        Wt[65536 + j] = __float2half(Wo[k * 64 + n]);
    }
}

// ------------------------------ phase bodies -------------------------------
// All phases are per-WAVE grid-stride loops; no LDS, no __syncthreads.

// GEMM: out[M x NC] = A(fp32 M x 128) @ W(fp16 fragment-major); fp32 accum.
// One 16-row m-tile per wave per iteration. B-fragments read directly from
// global Wt (32 KB, L2-resident across all XCDs; ~100 MB L2 reads/phase at
// 34 TB/s is ~3 us). If asrc!=null, GAT alpha logits from fp32 accumulators.
template <int NC, typename OT>
__device__ __forceinline__ void gemm_phase(
    const float* __restrict__ A, const __half* __restrict__ Wtp,
    const float* __restrict__ bias, OT* __restrict__ out,
    const float* __restrict__ asrc, const float* __restrict__ adst,
    float* __restrict__ alS, float* __restrict__ alD,
    int M, int wgid, int gwaves, int lane) {
    constexpr int NT = NC / 16;
    const int m16 = lane & 15, quad = lane >> 4;
    const f16x8* Wf = (const f16x8*)Wtp;
    const int tiles = (M + 15) >> 4;

    for (int t = wgid; t < tiles; t += gwaves) {
        const int row0 = t * 16;
        f16x8 af[4];
        {
            int row = row0 + m16;
            if (row > M - 1) row = M - 1;
            const float* ap = A + (size_t)row * 128 + quad * 8;
#pragma unroll
            for (int ks = 0; ks < 4; ++ks) {
                float4 lo = *(const float4*)(ap + ks * 32);
                float4 hi = *(const float4*)(ap + ks * 32 + 4);
                f16x8 v;
                v[0] = (_Float16)lo.x; v[1] = (_Float16)lo.y;
                v[2] = (_Float16)lo.z; v[3] = (_Float16)lo.w;
                v[4] = (_Float16)hi.x; v[5] = (_Float16)hi.y;
                v[6] = (_Float16)hi.z; v[7] = (_Float16)hi.w;
                af[ks] = v;
            }
        }

        f32x4 acc[NT];
#pragma unroll
        for (int nt = 0; nt < NT; ++nt)
            acc[nt] = (f32x4){0.f, 0.f, 0.f, 0.f};

#pragma unroll
        for (int ks = 0; ks < 4; ++ks) {
#pragma unroll
            for (int nt = 0; nt < NT; ++nt) {
                f16x8 bf = Wf[(nt * 4 + ks) * 64 + lane];
                acc[nt] = __builtin_amdgcn_mfma_f32_16x16x32_f16(
                    af[ks], bf, acc[nt], 0, 0, 0);
            }
        }

        if (asrc) {
            float sa[NT], da[NT];
#pragma unroll
            for (int nt = 0; nt < NT; ++nt) {
                sa[nt] = asrc[nt * 16 + m16];
                da[nt] = adst[nt * 16 + m16];
            }
#pragma unroll
            for (int r = 0; r < 4; ++r) {
                float s = 0.f, d = 0.f;
#pragma unroll
                for (int nt = 0; nt < NT; ++nt) {
                    s = fmaf(acc[nt][r], sa[nt], s);
                    d = fmaf(acc[nt][r], da[nt], d);
                }
#pragma unroll
                for (int off = 8; off > 0; off >>= 1) {
                    s += __shfl_xor(s, off);
                    d += __shfl_xor(d, off);
                }
                int row = row0 + quad * 4 + r;
                if (m16 == 0 && row < M) { alS[row] = s; alD[row] = d; }
            }
        }

#pragma unroll
        for (int nt = 0; nt < NT; ++nt) {
#pragma unroll
            for (int r = 0; r < 4; ++r) {
                int row = row0 + quad * 4 + r;
                if (row < M) {
                    float v = acc[nt][r];
                    int col = nt * 16 + m16;
                    if constexpr (sizeof(OT) == 2) {
                        ((__half*)out)[(size_t)row * NC + col] = __float2half(v);
                    } else {
                        ((float*)out)[(size_t)row * NC + col] = v + bias[col];
                    }
                }
            }
        }
    }
}

// Aggregation core (R1/R8-proven): lane = 16*g + q; quarter-wave g handles
// edge j+g of each group of 4; lane owns fp16 features 8q..8q+7 (16B).
// INVARIANT: lanes >= cnt hold wgt==0 and valid sid; guards wave-uniform.
__device__ __forceinline__ void gather_accum_h(
    const __half* __restrict__ xw, int q, int g, int cnt, int sid, float wgt,
    float acc[8]) {
    for (int base = 0; base < cnt; base += 32) {
        int c = cnt - base;           // wave-uniform
        float4 x[8];
        float w[8];
#pragma unroll
        for (int u = 0; u < 8; ++u) {
            if (u * 4 < c) {          // uniform guard
                int idx = base + 4 * u + g;
                int s = __shfl(sid, idx);
                w[u] = __shfl(wgt, idx);
                x[u] = *(const float4*)(xw + (size_t)s * 128 + q * 8);
            }
        }
#pragma unroll
        for (int u = 0; u < 8; ++u) {
            if (u * 4 < c) {          // uniform guard
                const __half2* h2 = (const __half2*)&x[u];
#pragma unroll
                for (int i = 0; i < 4; ++i) {
                    float2 cc = __half22float2(h2[i]);
                    acc[2 * i]     = fmaf(w[u], cc.x, acc[2 * i]);
                    acc[2 * i + 1] = fmaf(w[u], cc.y, acc[2 * i + 1]);
                }
            }
        }
    }
}

__device__ __forceinline__ void finish_store_q(
    float acc[8], const float* __restrict__ bias, float* __restrict__ out,
    int n, int q, int g) {
#pragma unroll
    for (int i = 0; i < 8; ++i) {
        acc[i] += __shfl_xor(acc[i], 16);
        acc[i] += __shfl_xor(acc[i], 32);
    }
    if (g == 0) {
        float4 b0 = ((const float4*)bias)[q * 2];
        float4 b1 = ((const float4*)bias)[q * 2 + 1];
        float4 r0, r1;
        r0.x = fmaxf(acc[0] + b0.x, 0.f);
        r0.y = fmaxf(acc[1] + b0.y, 0.f);
        r0.z = fmaxf(acc[2] + b0.z, 0.f);
        r0.w = fmaxf(acc[3] + b0.w, 0.f);
        r1.x = fmaxf(acc[4] + b1.x, 0.f);
        r1.y = fmaxf(acc[5] + b1.y, 0.f);
        r1.z = fmaxf(acc[6] + b1.z, 0.f);
        r1.w = fmaxf(acc[7] + b1.w, 0.f);
        float4* orow = (float4*)(out + (size_t)n * 128);
        orow[q * 2]     = r0;
        orow[q * 2 + 1] = r1;
    }
}

__device__ __forceinline__ void gcn_phase(
    const __half* __restrict__ xw, const int* __restrict__ rowp,
    const int* __restrict__ esrc, const float* __restrict__ inv,
    const float* __restrict__ bias, float* __restrict__ out,
    int Nn, int wgid, int gwaves, int lane) {
    const int q = lane & 15, g = lane >> 4;
    for (int n = wgid; n < Nn; n += gwaves) {
        int beg = rowp[n], end = rowp[n + 1];
        float invd = inv[n];
        float acc[8] = {0.f, 0.f, 0.f, 0.f, 0.f, 0.f, 0.f, 0.f};
        for (int base = beg; base < end; base += WAVE) {
            int e = base + lane;
            bool valid = (e < end);
            int sid = valid ? esrc[e] : 0;
            float c = valid ? invd * inv[sid] : 0.f;
            gather_accum_h(xw, q, g, min(WAVE, end - base), sid, c, acc);
        }
        finish_store_q(acc, bias, out, n, q, g);
    }
}

__device__ __forceinline__ void gat_phase(
    const __half* __restrict__ xw, const int* __restrict__ rowp,
    const int* __restrict__ esrc, const float* __restrict__ as_,
    const float* __restrict__ ad_, const float* __restrict__ bias,
    float* __restrict__ out, int Nn, int wgid, int gwaves, int lane) {
    const int q = lane & 15, g = lane >> 4;
    for (int n = wgid; n < Nn; n += gwaves) {
        int beg = rowp[n], end = rowp[n + 1];
        int deg = end - beg;
        float adn = ad_[n];
        float acc[8] = {0.f, 0.f, 0.f, 0.f, 0.f, 0.f, 0.f, 0.f};

        if (deg <= WAVE) {
            // fast path (deg<=64, ~all nodes): same math as R6-R9 fused path
            bool valid = (lane < deg);
            int sid = 0;
            float v = -1e30f;
            if (valid) {
                sid = esrc[beg + lane];
                float t = as_[sid] + adn;
                v = (t > 0.f) ? t : 0.2f * t;
            }
            float m = v;
#pragma unroll
            for (int off = 32; off > 0; off >>= 1) m = fmaxf(m, __shfl_xor(m, off));
            float ex = valid ? __expf(v - m) : 0.f;
            float ssum = ex;
#pragma unroll
            for (int off = 32; off > 0; off >>= 1) ssum += __shfl_xor(ssum, off);
            float wgt = ex * (1.f / ssum);   // invalid lanes: 0
            gather_accum_h(xw, q, g, deg, sid, wgt, acc);
        } else {
            // generic two-pass path (deg>64: essentially never at E/N=17)
            float m = -1e30f, ssum = 0.f;
            for (int e = beg + lane; e < end; e += WAVE) {
                float v = as_[esrc[e]] + adn;
                v = (v > 0.f) ? v : 0.2f * v;
                float mn = fmaxf(m, v);
                ssum = ssum * __expf(m - mn) + __expf(v - mn);
                m = mn;
            }
#pragma unroll
            for (int off = 32; off > 0; off >>= 1) {
                float mo = __shfl_xor(m, off);
                float so = __shfl_xor(ssum, off);
                float mn = fmaxf(m, mo);
                ssum = ssum * __expf(m - mn) + so * __expf(mo - mn);
                m = mn;
            }
            float rden = 1.f / ssum;
            for (int base = beg; base < end; base += WAVE) {
                int e = base + lane;
                bool valid = (e < end);
                int sid = valid ? esrc[e] : 0;
                float wgt = 0.f;
                if (valid) {
                    float v = as_[sid] + adn;
                    v = (v > 0.f) ? v : 0.2f * v;
                    wgt = __expf(v - m) * rden;
                }
                gather_accum_h(xw, q, g, min(WAVE, end - base), sid, wgt, acc);
            }
        }
        finish_store_q(acc, bias, out, n, q, g);
    }
}

// ------------------------------ mega kernel --------------------------------

struct MegaArgs {
    const float* x;
    const __half* Wt;
    const int* rowp;
    const int* esrc;
    const float* inv;
    const float *b1, *as1, *ad1, *bg1;
    const float *b2, *as2, *ad2, *bg2;
    const float* bo;
    __half* bufA;
    float *alS, *alD;
    float* outH;
    float* outZ;
    int Nn;
};

__device__ __forceinline__ void run_phase(const MegaArgs& a, int ph,
                                          int wgid, int gwaves, int lane) {
    switch (ph) {
    case 0: gemm_phase<128, __half>(a.x, a.Wt, nullptr, a.bufA,
                nullptr, nullptr, nullptr, nullptr, a.Nn, wgid, gwaves, lane); break;
    case 1: gcn_phase(a.bufA, a.rowp, a.esrc, a.inv, a.b1, a.outH,
                a.Nn, wgid, gwaves, lane); break;
    case 2: gemm_phase<128, __half>(a.outH, a.Wt + 16384, nullptr, a.bufA,
                a.as1, a.ad1, a.alS, a.alD, a.Nn, wgid, gwaves, lane); break;
    case 3: gat_phase(a.bufA, a.rowp, a.esrc, a.alS, a.alD, a.bg1, a.outH,
                a.Nn, wgid, gwaves, lane); break;
    case 4: gemm_phase<128, __half>(a.outH, a.Wt + 32768, nullptr, a.bufA,
                nullptr, nullptr, nullptr, nullptr, a.Nn, wgid, gwaves, lane); break;
    case 5: gcn_phase(a.bufA, a.rowp, a.esrc, a.inv, a.b2, a.outH,
                a.Nn, wgid, gwaves, lane); break;
    case 6: gemm_phase<128, __half>(a.outH, a.Wt + 49152, nullptr, a.bufA,
                a.as2, a.ad2, a.alS, a.alD, a.Nn, wgid, gwaves, lane); break;
    case 7: gat_phase(a.bufA, a.rowp, a.esrc, a.alS, a.alD, a.bg2, a.outH,
                a.Nn, wgid, gwaves, lane); break;
    case 8: gemm_phase<64, float>(a.outH, a.Wt + 65536, a.bo, a.outZ,
                nullptr, nullptr, nullptr, nullptr, a.Nn, wgid, gwaves, lane); break;
    }
}

__global__ __launch_bounds__(256, 4) void k_mega(MegaArgs a) {
    cg::grid_group grid = cg::this_grid();
    const int lane = threadIdx.x & 63;
    const int wgid = blockIdx.x * 4 + (threadIdx.x >> 6);
    const int gwaves = gridDim.x * 4;

    run_phase(a, 0, wgid, gwaves, lane); grid.sync();
    run_phase(a, 1, wgid, gwaves, lane); grid.sync();
    run_phase(a, 2, wgid, gwaves, lane); grid.sync();
    run_phase(a, 3, wgid, gwaves, lane); grid.sync();
    run_phase(a, 4, wgid, gwaves, lane); grid.sync();
    run_phase(a, 5, wgid, gwaves, lane); grid.sync();
    run_phase(a, 6, wgid, gwaves, lane); grid.sync();
    run_phase(a, 7, wgid, gwaves, lane); grid.sync();
    run_phase(a, 8, wgid, gwaves, lane);
}

// discrete fallback: same phase bodies, one dispatch per phase
__global__ __launch_bounds__(256, 4) void k_phase(MegaArgs a, int ph) {
    const int lane = threadIdx.x & 63;
    const int wgid = blockIdx.x * 4 + (threadIdx.x >> 6);
    const int gwaves = gridDim.x * 4;
    run_phase(a, ph, wgid, gwaves, lane);
}

// ------------------------------- launch ------------------------------------

extern "C" void kernel_launch(void* const* d_in, const int* in_sizes, int n_in,
                              void* d_out, int out_size, void* d_ws, size_t ws_size,
                              hipStream_t stream) {
    const float* x   = (const float*)d_in[0];
    const int*   ei  = (const int*)d_in[1];
    const float* W1  = (const float*)d_in[2];
    const float* b1  = (const float*)d_in[3];
    const float* Wg1 = (const float*)d_in[4];
    const float* as1 = (const float*)d_in[5];
    const float* ad1 = (const float*)d_in[6];
    const float* bg1 = (const float*)d_in[7];
    const float* W2  = (const float*)d_in[8];
    const float* b2  = (const float*)d_in[9];
    const float* Wg2 = (const float*)d_in[10];
    const float* as2 = (const float*)d_in[11];
    const float* ad2 = (const float*)d_in[12];
    const float* bg2 = (const float*)d_in[13];
    const float* Wo  = (const float*)d_in[14];
    const float* bo  = (const float*)d_in[15];

    const int Nn = in_sizes[0] / 128;
    const int E  = in_sizes[1] / 2;
    const int Et = E + Nn;
    const int H  = 128;
    const int nbuck = (Nn + BK - 1) / BK;   // 196

    float* outH = (float*)d_out;
    float* outZ = outH + (size_t)Nn * H;

    char* p = (char*)d_ws;
    auto carve = [&](size_t bytes) {
        char* r = p;
        p += (bytes + 255) & ~(size_t)255;
        return r;
    };
    __half* bufA = (__half*)carve((size_t)Nn * H * sizeof(__half));  // xw fp16
    __half* Wt   = (__half*)carve((size_t)73728 * sizeof(__half));   // fp16 W frags x5
    float* alS   = (float*)carve((size_t)Nn * sizeof(float));
    float* alD   = (float*)carve((size_t)Nn * sizeof(float));
    float* inv   = (float*)carve((size_t)Nn * sizeof(float));
    int*   rowp  = (int*)carve((size_t)(Nn + 1) * sizeof(int));
    int*   esrc  = (int*)carve((size_t)Et * sizeof(int));
    int2*  ebuf  = (int2*)carve((size_t)Et * sizeof(int2));
    int*   bcnt  = (int*)carve((size_t)nbuck * sizeof(int));
    int*   bbase = (int*)carve((size_t)(nbuck + 1) * sizeof(int));
    int*   bcur  = (int*)carve((size_t)nbuck * sizeof(int));
    (void)ws_size; (void)n_in; (void)out_size;

    const int scatB = (Et + CHUNK - 1) / CHUNK;   // 208

    // graph build (two-level bucket sort)
    k_zero_i32<<<1, 256, 0, stream>>>(bcnt, nbuck);
    k_bhist<<<104, 256, 0, stream>>>(ei, bcnt, E, Et, nbuck);
    k_bscan<<<1, 256, 0, stream>>>(bcnt, bbase, bcur, nbuck);
    k_bscatter<<<scatB, 256, 0, stream>>>(ei, bcur, ebuf, E, Et, nbuck);
    k_csr<<<nbuck, 256, 0, stream>>>(ebuf, bbase, rowp, inv, esrc, Nn, Et);
    k_wcvt<<<288, 256, 0, stream>>>(W1, Wg1, W2, Wg2, Wo, Wt);

    MegaArgs ma;
    ma.x = x; ma.Wt = Wt; ma.rowp = rowp; ma.esrc = esrc; ma.inv = inv;
    ma.b1 = b1; ma.as1 = as1; ma.ad1 = ad1; ma.bg1 = bg1;
    ma.b2 = b2; ma.as2 = as2; ma.ad2 = ad2; ma.bg2 = bg2;
    ma.bo = bo; ma.bufA = bufA; ma.alS = alS; ma.alD = alD;
    ma.outH = outH; ma.outZ = outZ; ma.Nn = Nn;

    // co-residency: query once; need >=2 blocks/CU to bother with cooperative
    static int coopBpc = -2;
    if (coopBpc == -2) {
        int bpc = 0;
        if (hipOccupancyMaxActiveBlocksPerMultiprocessor(&bpc, k_mega, 256, 0)
            != hipSuccess) bpc = 0;
        coopBpc = bpc;
    }

    bool done = false;
    if (coopBpc >= 2) {
        int G = (coopBpc >= 4 ? 4 : coopBpc) * 256;
        void* ka[] = { (void*)&ma };
        if (hipLaunchCooperativeKernel(k_mega, dim3(G), dim3(256), ka, 0, stream)
            == hipSuccess) done = true;
        else coopBpc = 0;   // don't retry cooperative on later calls
    }
    if (!done) {
        for (int ph = 0; ph < 9; ++ph)
            k_phase<<<1024, 256, 0, stream>>>(ma, ph);
    }
}

// Round 5
// 391.671 us; speedup vs baseline: 2.7867x; 2.7867x over previous
//
#include <hip/hip_runtime.h>
#include <hip/hip_bf16.h>
#include <hip/hip_fp16.h>

// ---------------------------------------------------------------------------
// GNN: h = relu(GCN(x)); h = relu(GAT(h)); h = relu(GCN(h)); h = relu(GAT(h));
//      z = h @ Wo + bo.  Outputs: [h (N*128), z (N*64)] fp32.
// R13: revert to R9 structure (378us, best proven). R10 (XCD slices), R11
//     (sorted gather), R12 (coop mega-kernel: VGPR-spill disaster, 270MB of
//     scratch traffic) all lost to it. Single controlled change this round:
//     k_gcn_agg2 processes TWO nodes per wave (both esrc chains + all 16
//     feature loads in flight before first wait) to test latency-bound vs
//     service-rate-bound for the 47us random gather. k_gat_agg is the exact
//     R9 single-node kernel = in-run control. Same math, bit-identical.
// ---------------------------------------------------------------------------

#define WAVE 64
#define BK 256        // nodes per bucket
#define CHUNK 4096    // edges per k_bscatter block

typedef _Float16 f16x8 __attribute__((ext_vector_type(8)));
typedef float f32x4 __attribute__((ext_vector_type(4)));

__global__ void k_zero_i32(int* __restrict__ p, int n) {
    int i = blockIdx.x * 256 + threadIdx.x;
    if (i < n) p[i] = 0;
}

// ------------------------------ graph build --------------------------------
// edge e in [0,E): (s,d) = (ei[e], ei[E+e]); e in [E,Et): self-loop (e-E,e-E)

__global__ __launch_bounds__(256) void k_bhist(
    const int* __restrict__ ei, int* __restrict__ bcnt,
    int E, int Et, int nbuck) {
    __shared__ int hist[256];
    int tid = threadIdx.x;
    if (tid < nbuck) hist[tid] = 0;
    __syncthreads();
    for (int e = blockIdx.x * 256 + tid; e < Et; e += gridDim.x * 256) {
        int d = (e < E) ? ei[E + e] : (e - E);
        atomicAdd(&hist[d >> 8], 1);
    }
    __syncthreads();
    if (tid < nbuck && hist[tid] > 0) atomicAdd(&bcnt[tid], hist[tid]);
}

__global__ void k_bscan(const int* __restrict__ bcnt, int* __restrict__ bbase,
                        int* __restrict__ bcur, int nbuck) {
    __shared__ int tmp[256];
    int tid = threadIdx.x;
    int v = (tid < nbuck) ? bcnt[tid] : 0;
    tmp[tid] = v;
    __syncthreads();
    for (int off = 1; off < 256; off <<= 1) {
        int t = (tid >= off) ? tmp[tid - off] : 0;
        __syncthreads();
        tmp[tid] += t;
        __syncthreads();
    }
    if (tid < nbuck) {
        int excl = tmp[tid] - v;
        bbase[tid] = excl;
        bcur[tid] = excl;
        if (tid == nbuck - 1) bbase[nbuck] = tmp[tid];
    }
}

__global__ __launch_bounds__(256) void k_bscatter(
    const int* __restrict__ ei, int* __restrict__ bcur,
    int2* __restrict__ ebuf, int E, int Et, int nbuck) {
    __shared__ int hist[256];
    __shared__ int base[256];
    __shared__ int off[256];
    constexpr int PT = CHUNK / 256;   // 16 edges per thread
    int tid = threadIdx.x;
    int cb = blockIdx.x * CHUNK;
    if (tid < nbuck) { hist[tid] = 0; off[tid] = 0; }
    __syncthreads();

    int sv[PT], dv[PT];
#pragma unroll
    for (int i = 0; i < PT; ++i) {
        int e = cb + i * 256 + tid;
        int s = 0, d = -1;
        if (e < Et) {
            if (e < E) { s = ei[e]; d = ei[E + e]; }
            else       { s = d = e - E; }
            atomicAdd(&hist[d >> 8], 1);
        }
        sv[i] = s; dv[i] = d;
    }
    __syncthreads();
    if (tid < nbuck && hist[tid] > 0)
        base[tid] = atomicAdd(&bcur[tid], hist[tid]);
    __syncthreads();
#pragma unroll
    for (int i = 0; i < PT; ++i) {
        if (dv[i] >= 0) {
            int b = dv[i] >> 8;
            int pos = base[b] + atomicAdd(&off[b], 1);
            ebuf[pos] = make_int2(sv[i], dv[i]);
        }
    }
}

__global__ __launch_bounds__(256) void k_csr(
    const int2* __restrict__ ebuf, const int* __restrict__ bbase,
    int* __restrict__ rowp, float* __restrict__ inv, int* __restrict__ esrc,
    int Nn, int Et) {
    __shared__ int hist[256];
    __shared__ int scan[256];
    __shared__ int cur[256];
    int tid = threadIdx.x;
    int b = blockIdx.x;
    int bb = bbase[b], cnt = bbase[b + 1] - bb;
    hist[tid] = 0;
    __syncthreads();
    for (int t = tid; t < cnt; t += 256)
        atomicAdd(&hist[ebuf[bb + t].y & 255], 1);
    __syncthreads();
    int v = hist[tid];
    scan[tid] = v;
    __syncthreads();
    for (int o = 1; o < 256; o <<= 1) {
        int t = (tid >= o) ? scan[tid - o] : 0;
        __syncthreads();
        scan[tid] += t;
        __syncthreads();
    }
    int excl = scan[tid] - v;
    int node = b * BK + tid;
    if (node < Nn) {
        rowp[node] = bb + excl;
        inv[node] = rsqrtf((float)v);
    }
    cur[tid] = excl;
    if (b == 0 && tid == 0) rowp[Nn] = Et;
    __syncthreads();
    for (int t = tid; t < cnt; t += 256) {
        int2 e = ebuf[bb + t];
        int pos = bb + atomicAdd(&cur[e.y & 255], 1);
        esrc[pos] = e.x;
    }
}

// -------------------- weight convert (fp32 -> fp16, fragment-major) --------
// Wt layout: [0]W1 [16384]Wg1 [32768]W2 [49152]Wg2 [65536]Wo
// Within each weight, B-fragments stored contiguously:
//   elem ((nt*4 + ks)*64 + lane)*8 + j  =  W[k][n]
//   with n = nt*16 + (lane&15), k = ks*32 + (lane>>4)*8 + j.

__global__ void k_wcvt(const float* __restrict__ W1, const float* __restrict__ Wg1,
                       const float* __restrict__ W2, const float* __restrict__ Wg2,
                       const float* __restrict__ Wo, __half* __restrict__ Wt) {
    int i = blockIdx.x * 256 + threadIdx.x;   // 73728 total
    if (i < 65536) {
        int w = i >> 14;
        int j = i & 16383;
        int nt = j >> 11, ks = (j >> 9) & 3, lane = (j >> 3) & 63, jj = j & 7;
        int n = nt * 16 + (lane & 15);
        int k = ks * 32 + (lane >> 4) * 8 + jj;
        const float* W = (w == 0) ? W1 : (w == 1) ? Wg1 : (w == 2) ? W2 : Wg2;
        Wt[i] = __float2half(W[k * 128 + n]);
    } else if (i < 73728) {
        int j = i - 65536;                    // 8192: Wo is 128x64 -> NT=4
        int nt = j >> 11, ks = (j >> 9) & 3, lane = (j >> 3) & 63, jj = j & 7;
        int n = nt * 16 + (lane & 15);
        int k = ks * 32 + (lane >> 4) * 8 + jj;
        Wt[65536 + j] = __float2half(Wo[k * 64 + n]);
    }
}

// ------------------------------ MFMA GEMM ----------------------------------
// out[M x NC] = A(fp32 M x 128) @ W(fp16, fragment-major Wt) ; fp32 accum.
// 256 thr = 4 waves, one 16-row m-tile per wave -> 64 rows/block, 782 blocks.
// fp16 output node-major [M][128]; fp32 output (NC=64, final) with bias.
// If asrc!=null, GAT alpha logits reduced from fp32 accumulators.

template <int NC, typename OT>
__global__ __launch_bounds__(256) void gemm_mfma(
    const float* __restrict__ A, const __half* __restrict__ Wt,
    const float* __restrict__ bias, OT* __restrict__ out,
    const float* __restrict__ asrc, const float* __restrict__ adst,
    float* __restrict__ alS, float* __restrict__ alD, int M) {
    constexpr int NT = NC / 16;
    __shared__ f16x8 Wl[NC * 16];             // NC*128 halfs, fragment-major
    const int tid = threadIdx.x;
    const int wv = tid >> 6, lane = tid & 63;
    const int m16 = lane & 15, quad = lane >> 4;

#pragma unroll
    for (int i = tid; i < NC * 16; i += 256)
        Wl[i] = ((const f16x8*)Wt)[i];
    __syncthreads();

    const int row0 = blockIdx.x * 64 + wv * 16;

    f16x8 af[4];
    {
        int row = row0 + m16;
        if (row > M - 1) row = M - 1;
        const float* ap = A + (size_t)row * 128 + quad * 8;
#pragma unroll
        for (int ks = 0; ks < 4; ++ks) {
            float4 lo = *(const float4*)(ap + ks * 32);
            float4 hi = *(const float4*)(ap + ks * 32 + 4);
            f16x8 v;
            v[0] = (_Float16)lo.x; v[1] = (_Float16)lo.y;
            v[2] = (_Float16)lo.z; v[3] = (_Float16)lo.w;
            v[4] = (_Float16)hi.x; v[5] = (_Float16)hi.y;
            v[6] = (_Float16)hi.z; v[7] = (_Float16)hi.w;
            af[ks] = v;
        }
    }

    f32x4 acc[NT];
#pragma unroll
    for (int nt = 0; nt < NT; ++nt)
        acc[nt] = (f32x4){0.f, 0.f, 0.f, 0.f};

#pragma unroll
    for (int ks = 0; ks < 4; ++ks) {
#pragma unroll
        for (int nt = 0; nt < NT; ++nt) {
            f16x8 bf = Wl[(nt * 4 + ks) * 64 + lane];
            acc[nt] = __builtin_amdgcn_mfma_f32_16x16x32_f16(
                af[ks], bf, acc[nt], 0, 0, 0);
        }
    }

    // fused GAT alpha: s = xw.asrc, d = xw.adst per row (from fp32 accum)
    if (asrc) {
        float sa[NT], da[NT];
#pragma unroll
        for (int nt = 0; nt < NT; ++nt) {
            sa[nt] = asrc[nt * 16 + m16];
            da[nt] = adst[nt * 16 + m16];
        }
#pragma unroll
        for (int r = 0; r < 4; ++r) {
            float s = 0.f, d = 0.f;
#pragma unroll
            for (int nt = 0; nt < NT; ++nt) {
                s = fmaf(acc[nt][r], sa[nt], s);
                d = fmaf(acc[nt][r], da[nt], d);
            }
#pragma unroll
            for (int off = 8; off > 0; off >>= 1) {
                s += __shfl_xor(s, off);
                d += __shfl_xor(d, off);
            }
            int row = row0 + quad * 4 + r;
            if (m16 == 0 && row < M) { alS[row] = s; alD[row] = d; }
        }
    }

#pragma unroll
    for (int nt = 0; nt < NT; ++nt) {
#pragma unroll
        for (int r = 0; r < 4; ++r) {
            int row = row0 + quad * 4 + r;
            if (row < M) {
                float v = acc[nt][r];
                int col = nt * 16 + m16;
                if constexpr (sizeof(OT) == 2) {
                    ((__half*)out)[(size_t)row * NC + col] = __float2half(v);
                } else {
                    ((float*)out)[(size_t)row * NC + col] = v + bias[col];
                }
            }
        }
    }
}

// --------------------------- aggregation kernels ---------------------------
// Base structure (R1-proven): one wave per destination node. lane = 16*g + q:
// quarter-wave g handles edge j+g of each group of 4; lane owns fp16 features
// 8q..8q+7 (16 B dwordx4). INVARIANT: lanes with index >= cnt hold wgt == 0
// and a valid sid (0 ok); all guards wave-uniform so shfl runs with full exec.

__device__ __forceinline__ void gather_accum_h(
    const __half* __restrict__ xw, int q, int g, int cnt, int sid, float wgt,
    float acc[8]) {
    for (int base = 0; base < cnt; base += 32) {
        int c = cnt - base;           // wave-uniform
        float4 x[8];
        float w[8];
#pragma unroll
        for (int u = 0; u < 8; ++u) {
            if (u * 4 < c) {          // uniform guard
                int idx = base + 4 * u + g;
                int s = __shfl(sid, idx);
                w[u] = __shfl(wgt, idx);
                x[u] = *(const float4*)(xw + (size_t)s * 128 + q * 8);
            }
        }
#pragma unroll
        for (int u = 0; u < 8; ++u) {
            if (u * 4 < c) {          // uniform guard
                const __half2* h2 = (const __half2*)&x[u];
#pragma unroll
                for (int i = 0; i < 4; ++i) {
                    float2 cc = __half22float2(h2[i]);
                    acc[2 * i]     = fmaf(w[u], cc.x, acc[2 * i]);
                    acc[2 * i + 1] = fmaf(w[u], cc.y, acc[2 * i + 1]);
                }
            }
        }
    }
}

__device__ __forceinline__ void finish_store_q(
    float acc[8], const float* __restrict__ bias, float* __restrict__ out,
    int n, int q, int g) {
#pragma unroll
    for (int i = 0; i < 8; ++i) {
        acc[i] += __shfl_xor(acc[i], 16);
        acc[i] += __shfl_xor(acc[i], 32);
    }
    if (g == 0) {
        float4 b0 = ((const float4*)bias)[q * 2];
        float4 b1 = ((const float4*)bias)[q * 2 + 1];
        float4 r0, r1;
        r0.x = fmaxf(acc[0] + b0.x, 0.f);
        r0.y = fmaxf(acc[1] + b0.y, 0.f);
        r0.z = fmaxf(acc[2] + b0.z, 0.f);
        r0.w = fmaxf(acc[3] + b0.w, 0.f);
        r1.x = fmaxf(acc[4] + b1.x, 0.f);
        r1.y = fmaxf(acc[5] + b1.y, 0.f);
        r1.z = fmaxf(acc[6] + b1.z, 0.f);
        r1.w = fmaxf(acc[7] + b1.w, 0.f);
        float4* orow = (float4*)(out + (size_t)n * 128);
        orow[q * 2]     = r0;
        orow[q * 2 + 1] = r1;
    }
}

__device__ __forceinline__ void acc8h(float acc[8], float4 v, float w) {
    const __half2* h2 = (const __half2*)&v;
#pragma unroll
    for (int i = 0; i < 4; ++i) {
        float2 f = __half22float2(h2[i]);
        acc[2 * i]     = fmaf(w, f.x, acc[2 * i]);
        acc[2 * i + 1] = fmaf(w, f.y, acc[2 * i + 1]);
    }
}

// R13: TWO nodes per wave. Both esrc chains issue up front; all 16 feature
// loads (8 per node) are outstanding before the first accumulate waits.
// Doubles per-wave MLP on an identical access pattern (latency-bound test).
__global__ __launch_bounds__(256, 4) void k_gcn_agg2(
    const __half* __restrict__ xw, const int* __restrict__ rowp,
    const int* __restrict__ esrc, const float* __restrict__ inv,
    const float* __restrict__ bias, float* __restrict__ out, int Nn) {
    int gid = blockIdx.x * 256 + threadIdx.x;
    int wid = gid >> 6, lane = gid & 63;
    int n0 = wid * 2, n1 = n0 + 1;
    if (n0 >= Nn) return;
    bool has1 = (n1 < Nn);                     // wave-uniform
    int q = lane & 15, g = lane >> 4;

    int beg0 = rowp[n0], end0 = rowp[n0 + 1];
    int beg1 = has1 ? rowp[n1] : 0;
    int end1 = has1 ? rowp[n1 + 1] : 0;
    int c0 = end0 - beg0, c1 = end1 - beg1;
    float invd0 = inv[n0];
    float invd1 = has1 ? inv[n1] : 0.f;

    float acc0[8] = {0.f, 0.f, 0.f, 0.f, 0.f, 0.f, 0.f, 0.f};
    float acc1[8] = {0.f, 0.f, 0.f, 0.f, 0.f, 0.f, 0.f, 0.f};

    if (c0 <= WAVE && c1 <= WAVE) {            // fast path: ~always
        int e0 = beg0 + lane;
        bool v0 = (e0 < end0);
        int sid0 = v0 ? esrc[e0] : 0;
        int e1 = beg1 + lane;
        bool v1 = has1 && (e1 < end1);
        int sid1 = v1 ? esrc[e1] : 0;
        float w0 = v0 ? invd0 * inv[sid0] : 0.f;
        float w1 = v1 ? invd1 * inv[sid1] : 0.f;

        float4 xa[8], xb[8];
        float wa[8], wb[8];
#pragma unroll
        for (int u = 0; u < 8; ++u) {
            if (u * 4 < c0) {                  // uniform guard
                int idx = 4 * u + g;
                int s = __shfl(sid0, idx);
                wa[u] = __shfl(w0, idx);
                xa[u] = *(const float4*)(xw + (size_t)s * 128 + q * 8);
            }
        }
#pragma unroll
        for (int u = 0; u < 8; ++u) {
            if (u * 4 < c1) {                  // uniform guard
                int idx = 4 * u + g;
                int s = __shfl(sid1, idx);
                wb[u] = __shfl(w1, idx);
                xb[u] = *(const float4*)(xw + (size_t)s * 128 + q * 8);
            }
        }
#pragma unroll
        for (int u = 0; u < 8; ++u)
            if (u * 4 < c0) acc8h(acc0, xa[u], wa[u]);
#pragma unroll
        for (int u = 0; u < 8; ++u)
            if (u * 4 < c1) acc8h(acc1, xb[u], wb[u]);
    } else {                                   // generic (deg>64): rare
        for (int base = beg0; base < end0; base += WAVE) {
            int e = base + lane;
            bool valid = (e < end0);
            int sid = valid ? esrc[e] : 0;
            float c = valid ? invd0 * inv[sid] : 0.f;
            gather_accum_h(xw, q, g, min(WAVE, end0 - base), sid, c, acc0);
        }
        for (int base = beg1; base < end1; base += WAVE) {
            int e = base + lane;
            bool valid = (e < end1);
            int sid = valid ? esrc[e] : 0;
            float c = valid ? invd1 * inv[sid] : 0.f;
            gather_accum_h(xw, q, g, min(WAVE, end1 - base), sid, c, acc1);
        }
    }

    finish_store_q(acc0, bias, out, n0, q, g);
    if (has1) finish_store_q(acc1, bias, out, n1, q, g);
}

// GAT agg: exact R9 single-node structure (in-run CONTROL for the ILP test).
__global__ __launch_bounds__(256) void k_gat_agg(
    const __half* __restrict__ xw, const int* __restrict__ rowp,
    const int* __restrict__ esrc, const float* __restrict__ as_,
    const float* __restrict__ ad_, const float* __restrict__ bias,
    float* __restrict__ out, int Nn) {
    int gid = blockIdx.x * 256 + threadIdx.x;
    int n = gid >> 6, lane = gid & 63;
    if (n >= Nn) return;
    int q = lane & 15, g = lane >> 4;
    int beg = rowp[n], end = rowp[n + 1];
    int deg = end - beg;
    float adn = ad_[n];
    float acc[8] = {0.f, 0.f, 0.f, 0.f, 0.f, 0.f, 0.f, 0.f};

    if (deg <= WAVE) {
        // fused path (deg<=64, ~all nodes): edge data loaded once, logit in reg
        bool valid = (lane < deg);
        int sid = 0;
        float v = -1e30f;
        if (valid) {
            sid = esrc[beg + lane];
            float t = as_[sid] + adn;
            v = (t > 0.f) ? t : 0.2f * t;
        }
        float m = v;
#pragma unroll
        for (int off = 32; off > 0; off >>= 1) m = fmaxf(m, __shfl_xor(m, off));
        float ex = valid ? __expf(v - m) : 0.f;
        float ssum = ex;
#pragma unroll
        for (int off = 32; off > 0; off >>= 1) ssum += __shfl_xor(ssum, off);
        float wgt = ex * (1.f / ssum);   // invalid lanes: 0
        gather_accum_h(xw, q, g, deg, sid, wgt, acc);
    } else {
        // generic two-pass path (deg>64: essentially never at E/N=16)
        float m = -1e30f, ssum = 0.f;
        for (int e = beg + lane; e < end; e += WAVE) {
            float v = as_[esrc[e]] + adn;
            v = (v > 0.f) ? v : 0.2f * v;
            float mn = fmaxf(m, v);
            ssum = ssum * __expf(m - mn) + __expf(v - mn);
            m = mn;
        }
#pragma unroll
        for (int off = 32; off > 0; off >>= 1) {
            float mo = __shfl_xor(m, off);
            float so = __shfl_xor(ssum, off);
            float mn = fmaxf(m, mo);
            ssum = ssum * __expf(m - mn) + so * __expf(mo - mn);
            m = mn;
        }
        float rden = 1.f / ssum;
        for (int base = beg; base < end; base += WAVE) {
            int e = base + lane;
            bool valid = (e < end);
            int sid = valid ? esrc[e] : 0;
            float wgt = 0.f;
            if (valid) {
                float v = as_[sid] + adn;
                v = (v > 0.f) ? v : 0.2f * v;
                wgt = __expf(v - m) * rden;
            }
            gather_accum_h(xw, q, g, min(WAVE, end - base), sid, wgt, acc);
        }
    }
    finish_store_q(acc, bias, out, n, q, g);
}

// ------------------------------- launch ------------------------------------

extern "C" void kernel_launch(void* const* d_in, const int* in_sizes, int n_in,
                              void* d_out, int out_size, void* d_ws, size_t ws_size,
                              hipStream_t stream) {
    const float* x   = (const float*)d_in[0];
    const int*   ei  = (const int*)d_in[1];
    const float* W1  = (const float*)d_in[2];
    const float* b1  = (const float*)d_in[3];
    const float* Wg1 = (const float*)d_in[4];
    const float* as1 = (const float*)d_in[5];
    const float* ad1 = (const float*)d_in[6];
    const float* bg1 = (const float*)d_in[7];
    const float* W2  = (const float*)d_in[8];
    const float* b2  = (const float*)d_in[9];
    const float* Wg2 = (const float*)d_in[10];
    const float* as2 = (const float*)d_in[11];
    const float* ad2 = (const float*)d_in[12];
    const float* bg2 = (const float*)d_in[13];
    const float* Wo  = (const float*)d_in[14];
    const float* bo  = (const float*)d_in[15];

    const int Nn = in_sizes[0] / 128;
    const int E  = in_sizes[1] / 2;
    const int Et = E + Nn;
    const int H  = 128;
    const int nbuck = (Nn + BK - 1) / BK;   // 196

    float* outH = (float*)d_out;
    float* outZ = outH + (size_t)Nn * H;

    char* p = (char*)d_ws;
    auto carve = [&](size_t bytes) {
        char* r = p;
        p += (bytes + 255) & ~(size_t)255;
        return r;
    };
    __half* bufA = (__half*)carve((size_t)Nn * H * sizeof(__half));  // xw fp16
    __half* Wt   = (__half*)carve((size_t)73728 * sizeof(__half));   // fp16 W frags x5
    float* alS   = (float*)carve((size_t)Nn * sizeof(float));
    float* alD   = (float*)carve((size_t)Nn * sizeof(float));
    float* inv   = (float*)carve((size_t)Nn * sizeof(float));
    int*   rowp  = (int*)carve((size_t)(Nn + 1) * sizeof(int));
    int*   esrc  = (int*)carve((size_t)Et * sizeof(int));
    int2*  ebuf  = (int2*)carve((size_t)Et * sizeof(int2));
    int*   bcnt  = (int*)carve((size_t)nbuck * sizeof(int));
    int*   bbase = (int*)carve((size_t)(nbuck + 1) * sizeof(int));
    int*   bcur  = (int*)carve((size_t)nbuck * sizeof(int));
    (void)ws_size; (void)n_in; (void)out_size;

    const int aggBlocks  = (Nn * WAVE + 255) / 256;            // 12500: 1 node/wave
    const int gcn2Blocks = (((Nn + 1) / 2) * WAVE + 255) / 256; // 6250: 2 nodes/wave
    const int gemmB = (Nn + 63) / 64;                           // 782
    const int scatB = (Et + CHUNK - 1) / CHUNK;                 // 208

    // graph build (two-level bucket sort)
    k_zero_i32<<<1, 256, 0, stream>>>(bcnt, nbuck);
    k_bhist<<<104, 256, 0, stream>>>(ei, bcnt, E, Et, nbuck);
    k_bscan<<<1, 256, 0, stream>>>(bcnt, bbase, bcur, nbuck);
    k_bscatter<<<scatB, 256, 0, stream>>>(ei, bcur, ebuf, E, Et, nbuck);
    k_csr<<<nbuck, 256, 0, stream>>>(ebuf, bbase, rowp, inv, esrc, Nn, Et);
    k_wcvt<<<288, 256, 0, stream>>>(W1, Wg1, W2, Wg2, Wo, Wt);

    gemm_mfma<128, __half><<<gemmB, 256, 0, stream>>>(
        x, Wt, nullptr, bufA, nullptr, nullptr, nullptr, nullptr, Nn);
    k_gcn_agg2<<<gcn2Blocks, 256, 0, stream>>>(bufA, rowp, esrc, inv, b1, outH, Nn);

    gemm_mfma<128, __half><<<gemmB, 256, 0, stream>>>(
        outH, Wt + 16384, nullptr, bufA, as1, ad1, alS, alD, Nn);
    k_gat_agg<<<aggBlocks, 256, 0, stream>>>(bufA, rowp, esrc, alS, alD, bg1, outH, Nn);

    gemm_mfma<128, __half><<<gemmB, 256, 0, stream>>>(
        outH, Wt + 32768, nullptr, bufA, nullptr, nullptr, nullptr, nullptr, Nn);
    k_gcn_agg2<<<gcn2Blocks, 256, 0, stream>>>(bufA, rowp, esrc, inv, b2, outH, Nn);

    gemm_mfma<128, __half><<<gemmB, 256, 0, stream>>>(
        outH, Wt + 49152, nullptr, bufA, as2, ad2, alS, alD, Nn);
    k_gat_agg<<<aggBlocks, 256, 0, stream>>>(bufA, rowp, esrc, alS, alD, bg2, outH, Nn);

    gemm_mfma<64, float><<<gemmB, 256, 0, stream>>>(
        outH, Wt + 65536, bo, outZ, nullptr, nullptr, nullptr, nullptr, Nn);
}

// Round 6
// 374.365 us; speedup vs baseline: 2.9155x; 1.0462x over previous
//
#include <hip/hip_runtime.h>
#include <hip/hip_bf16.h>
#include <hip/hip_fp16.h>

// ---------------------------------------------------------------------------
// GNN: h = relu(GCN(x)); h = relu(GAT(h)); h = relu(GCN(h)); h = relu(GAT(h));
//      z = h @ Wo + bo.  Outputs: [h (N*128), z (N*64)] fp32.
// R14: consolidation. R13 verdict: gather is SERVICE-RATE-bound (2-node ILP
//     regressed 47->52us; VALUBusy fell) — each agg's ~85MB L2-miss traffic
//     = 8 XCDs x 12.8MB compulsory table refill at ~2.4TB/s = ~45us floor.
//     R13's agg2 also dropped edges 32..63 (deg>32) — REVERTED to R9 agg.
//     Additive wins this round: (1) aggs 1-3 write h as fp16 (next GEMM
//     rounded A to fp16 anyway -> bit-identical chain; halves agg writes and
//     GEMM-A reads), final GAT agg still writes fp32 outH (required output);
//     (2) k_wcvt merged into k_bhist, k_zero -> hipMemsetAsync (15->13
//     dispatches). GEMM (R9 frag-major) and build (R7) otherwise unchanged.
// ---------------------------------------------------------------------------

#define WAVE 64
#define BK 256        // nodes per bucket
#define CHUNK 4096    // edges per k_bscatter block

typedef _Float16 f16x8 __attribute__((ext_vector_type(8)));
typedef float f32x4 __attribute__((ext_vector_type(4)));

// ------------------------------ graph build --------------------------------
// edge e in [0,E): (s,d) = (ei[e], ei[E+e]); e in [E,Et): self-loop (e-E,e-E)
// Merged with weight convert (independent work, saves a dispatch):
// Wt layout: [0]W1 [16384]Wg1 [32768]W2 [49152]Wg2 [65536]Wo, fragment-major:
//   elem ((nt*4+ks)*64+lane)*8+j = W[k][n], n = nt*16+(lane&15),
//   k = ks*32+(lane>>4)*8+j.

__global__ __launch_bounds__(256) void k_bhist_wcvt(
    const int* __restrict__ ei, int* __restrict__ bcnt, int E, int Et, int nbuck,
    const float* __restrict__ W1, const float* __restrict__ Wg1,
    const float* __restrict__ W2, const float* __restrict__ Wg2,
    const float* __restrict__ Wo, __half* __restrict__ Wt) {
    __shared__ int hist[256];
    int tid = threadIdx.x;
    if (tid < nbuck) hist[tid] = 0;
    __syncthreads();
    for (int e = blockIdx.x * 256 + tid; e < Et; e += gridDim.x * 256) {
        int d = (e < E) ? ei[E + e] : (e - E);
        atomicAdd(&hist[d >> 8], 1);
    }
    __syncthreads();
    if (tid < nbuck && hist[tid] > 0) atomicAdd(&bcnt[tid], hist[tid]);

    // weight convert: 73728 elems over 288 blocks x 256 threads exactly
    int i = blockIdx.x * 256 + tid;
    if (i < 65536) {
        int w = i >> 14;
        int j = i & 16383;
        int nt = j >> 11, ks = (j >> 9) & 3, lane = (j >> 3) & 63, jj = j & 7;
        int n = nt * 16 + (lane & 15);
        int k = ks * 32 + (lane >> 4) * 8 + jj;
        const float* W = (w == 0) ? W1 : (w == 1) ? Wg1 : (w == 2) ? W2 : Wg2;
        Wt[i] = __float2half(W[k * 128 + n]);
    } else if (i < 73728) {
        int j = i - 65536;                    // 8192: Wo is 128x64 -> NT=4
        int nt = j >> 11, ks = (j >> 9) & 3, lane = (j >> 3) & 63, jj = j & 7;
        int n = nt * 16 + (lane & 15);
        int k = ks * 32 + (lane >> 4) * 8 + jj;
        Wt[65536 + j] = __float2half(Wo[k * 64 + n]);
    }
}

__global__ void k_bscan(const int* __restrict__ bcnt, int* __restrict__ bbase,
                        int* __restrict__ bcur, int nbuck) {
    __shared__ int tmp[256];
    int tid = threadIdx.x;
    int v = (tid < nbuck) ? bcnt[tid] : 0;
    tmp[tid] = v;
    __syncthreads();
    for (int off = 1; off < 256; off <<= 1) {
        int t = (tid >= off) ? tmp[tid - off] : 0;
        __syncthreads();
        tmp[tid] += t;
        __syncthreads();
    }
    if (tid < nbuck) {
        int excl = tmp[tid] - v;
        bbase[tid] = excl;
        bcur[tid] = excl;
        if (tid == nbuck - 1) bbase[nbuck] = tmp[tid];
    }
}

__global__ __launch_bounds__(256) void k_bscatter(
    const int* __restrict__ ei, int* __restrict__ bcur,
    int2* __restrict__ ebuf, int E, int Et, int nbuck) {
    __shared__ int hist[256];
    __shared__ int base[256];
    __shared__ int off[256];
    constexpr int PT = CHUNK / 256;   // 16 edges per thread
    int tid = threadIdx.x;
    int cb = blockIdx.x * CHUNK;
    if (tid < nbuck) { hist[tid] = 0; off[tid] = 0; }
    __syncthreads();

    int sv[PT], dv[PT];
#pragma unroll
    for (int i = 0; i < PT; ++i) {
        int e = cb + i * 256 + tid;
        int s = 0, d = -1;
        if (e < Et) {
            if (e < E) { s = ei[e]; d = ei[E + e]; }
            else       { s = d = e - E; }
            atomicAdd(&hist[d >> 8], 1);
        }
        sv[i] = s; dv[i] = d;
    }
    __syncthreads();
    if (tid < nbuck && hist[tid] > 0)
        base[tid] = atomicAdd(&bcur[tid], hist[tid]);
    __syncthreads();
#pragma unroll
    for (int i = 0; i < PT; ++i) {
        if (dv[i] >= 0) {
            int b = dv[i] >> 8;
            int pos = base[b] + atomicAdd(&off[b], 1);
            ebuf[pos] = make_int2(sv[i], dv[i]);
        }
    }
}

__global__ __launch_bounds__(256) void k_csr(
    const int2* __restrict__ ebuf, const int* __restrict__ bbase,
    int* __restrict__ rowp, float* __restrict__ inv, int* __restrict__ esrc,
    int Nn, int Et) {
    __shared__ int hist[256];
    __shared__ int scan[256];
    __shared__ int cur[256];
    int tid = threadIdx.x;
    int b = blockIdx.x;
    int bb = bbase[b], cnt = bbase[b + 1] - bb;
    hist[tid] = 0;
    __syncthreads();
    for (int t = tid; t < cnt; t += 256)
        atomicAdd(&hist[ebuf[bb + t].y & 255], 1);
    __syncthreads();
    int v = hist[tid];
    scan[tid] = v;
    __syncthreads();
    for (int o = 1; o < 256; o <<= 1) {
        int t = (tid >= o) ? scan[tid - o] : 0;
        __syncthreads();
        scan[tid] += t;
        __syncthreads();
    }
    int excl = scan[tid] - v;
    int node = b * BK + tid;
    if (node < Nn) {
        rowp[node] = bb + excl;
        inv[node] = rsqrtf((float)v);
    }
    cur[tid] = excl;
    if (b == 0 && tid == 0) rowp[Nn] = Et;
    __syncthreads();
    for (int t = tid; t < cnt; t += 256) {
        int2 e = ebuf[bb + t];
        int pos = bb + atomicAdd(&cur[e.y & 255], 1);
        esrc[pos] = e.x;
    }
}

// ------------------------------ MFMA GEMM ----------------------------------
// out[M x NC] = A(M x 128, fp32 OR fp16) @ W(fp16, fragment-major Wt).
// 256 thr = 4 waves, one 16-row m-tile per wave -> 64 rows/block, 782 blocks.
// fp16 A is read directly (no cvt); fp32 A converted in-register (same RN
// rounding as storing fp16 -> bit-identical results either way).
// If asrc!=null, GAT alpha logits reduced from fp32 accumulators.

template <typename AT, int NC, typename OT>
__global__ __launch_bounds__(256) void gemm_mfma(
    const AT* __restrict__ A, const __half* __restrict__ Wt,
    const float* __restrict__ bias, OT* __restrict__ out,
    const float* __restrict__ asrc, const float* __restrict__ adst,
    float* __restrict__ alS, float* __restrict__ alD, int M) {
    constexpr int NT = NC / 16;
    __shared__ f16x8 Wl[NC * 16];             // NC*128 halfs, fragment-major
    const int tid = threadIdx.x;
    const int wv = tid >> 6, lane = tid & 63;
    const int m16 = lane & 15, quad = lane >> 4;

#pragma unroll
    for (int i = tid; i < NC * 16; i += 256)
        Wl[i] = ((const f16x8*)Wt)[i];
    __syncthreads();

    const int row0 = blockIdx.x * 64 + wv * 16;

    f16x8 af[4];
    {
        int row = row0 + m16;
        if (row > M - 1) row = M - 1;
        if constexpr (sizeof(AT) == 2) {
            const __half* ap = (const __half*)A + (size_t)row * 128 + quad * 8;
#pragma unroll
            for (int ks = 0; ks < 4; ++ks)
                af[ks] = *(const f16x8*)(ap + ks * 32);
        } else {
            const float* ap = (const float*)A + (size_t)row * 128 + quad * 8;
#pragma unroll
            for (int ks = 0; ks < 4; ++ks) {
                float4 lo = *(const float4*)(ap + ks * 32);
                float4 hi = *(const float4*)(ap + ks * 32 + 4);
                f16x8 v;
                v[0] = (_Float16)lo.x; v[1] = (_Float16)lo.y;
                v[2] = (_Float16)lo.z; v[3] = (_Float16)lo.w;
                v[4] = (_Float16)hi.x; v[5] = (_Float16)hi.y;
                v[6] = (_Float16)hi.z; v[7] = (_Float16)hi.w;
                af[ks] = v;
            }
        }
    }

    f32x4 acc[NT];
#pragma unroll
    for (int nt = 0; nt < NT; ++nt)
        acc[nt] = (f32x4){0.f, 0.f, 0.f, 0.f};

#pragma unroll
    for (int ks = 0; ks < 4; ++ks) {
#pragma unroll
        for (int nt = 0; nt < NT; ++nt) {
            f16x8 bf = Wl[(nt * 4 + ks) * 64 + lane];
            acc[nt] = __builtin_amdgcn_mfma_f32_16x16x32_f16(
                af[ks], bf, acc[nt], 0, 0, 0);
        }
    }

    // fused GAT alpha: s = xw.asrc, d = xw.adst per row (from fp32 accum)
    if (asrc) {
        float sa[NT], da[NT];
#pragma unroll
        for (int nt = 0; nt < NT; ++nt) {
            sa[nt] = asrc[nt * 16 + m16];
            da[nt] = adst[nt * 16 + m16];
        }
#pragma unroll
        for (int r = 0; r < 4; ++r) {
            float s = 0.f, d = 0.f;
#pragma unroll
            for (int nt = 0; nt < NT; ++nt) {
                s = fmaf(acc[nt][r], sa[nt], s);
                d = fmaf(acc[nt][r], da[nt], d);
            }
#pragma unroll
            for (int off = 8; off > 0; off >>= 1) {
                s += __shfl_xor(s, off);
                d += __shfl_xor(d, off);
            }
            int row = row0 + quad * 4 + r;
            if (m16 == 0 && row < M) { alS[row] = s; alD[row] = d; }
        }
    }

#pragma unroll
    for (int nt = 0; nt < NT; ++nt) {
#pragma unroll
        for (int r = 0; r < 4; ++r) {
            int row = row0 + quad * 4 + r;
            if (row < M) {
                float v = acc[nt][r];
                int col = nt * 16 + m16;
                if constexpr (sizeof(OT) == 2) {
                    ((__half*)out)[(size_t)row * NC + col] = __float2half(v);
                } else {
                    ((float*)out)[(size_t)row * NC + col] = v + bias[col];
                }
            }
        }
    }
}

// --------------------------- aggregation kernels ---------------------------
// R9-proven structure: one wave per destination node. lane = 16*g + q:
// quarter-wave g handles edge j+g of each group of 4; lane owns fp16 features
// 8q..8q+7 (16 B dwordx4). INVARIANT: lanes with index >= cnt hold wgt == 0
// and a valid sid (0 ok); all guards wave-uniform so shfl runs with full exec.
// Output templated: fp16 for intermediate h (layers 1-3; next GEMM rounded to
// fp16 anyway -> bit-identical), fp32 for the final h (required output).

__device__ __forceinline__ void gather_accum_h(
    const __half* __restrict__ xw, int q, int g, int cnt, int sid, float wgt,
    float acc[8]) {
    for (int base = 0; base < cnt; base += 32) {
        int c = cnt - base;           // wave-uniform
        float4 x[8];
        float w[8];
#pragma unroll
        for (int u = 0; u < 8; ++u) {
            if (u * 4 < c) {          // uniform guard
                int idx = base + 4 * u + g;
                int s = __shfl(sid, idx);
                w[u] = __shfl(wgt, idx);
                x[u] = *(const float4*)(xw + (size_t)s * 128 + q * 8);
            }
        }
#pragma unroll
        for (int u = 0; u < 8; ++u) {
            if (u * 4 < c) {          // uniform guard
                const __half2* h2 = (const __half2*)&x[u];
#pragma unroll
                for (int i = 0; i < 4; ++i) {
                    float2 cc = __half22float2(h2[i]);
                    acc[2 * i]     = fmaf(w[u], cc.x, acc[2 * i]);
                    acc[2 * i + 1] = fmaf(w[u], cc.y, acc[2 * i + 1]);
                }
            }
        }
    }
}

template <typename OT>
__device__ __forceinline__ void finish_store_q(
    float acc[8], const float* __restrict__ bias, OT* __restrict__ out,
    int n, int q, int g) {
#pragma unroll
    for (int i = 0; i < 8; ++i) {
        acc[i] += __shfl_xor(acc[i], 16);
        acc[i] += __shfl_xor(acc[i], 32);
    }
    if (g == 0) {
        float4 b0 = ((const float4*)bias)[q * 2];
        float4 b1 = ((const float4*)bias)[q * 2 + 1];
        float r[8];
        r[0] = fmaxf(acc[0] + b0.x, 0.f);
        r[1] = fmaxf(acc[1] + b0.y, 0.f);
        r[2] = fmaxf(acc[2] + b0.z, 0.f);
        r[3] = fmaxf(acc[3] + b0.w, 0.f);
        r[4] = fmaxf(acc[4] + b1.x, 0.f);
        r[5] = fmaxf(acc[5] + b1.y, 0.f);
        r[6] = fmaxf(acc[6] + b1.z, 0.f);
        r[7] = fmaxf(acc[7] + b1.w, 0.f);
        if constexpr (sizeof(OT) == 2) {
            f16x8 hv;
#pragma unroll
            for (int i = 0; i < 8; ++i) hv[i] = (_Float16)r[i];
            *(f16x8*)((__half*)out + (size_t)n * 128 + q * 8) = hv;
        } else {
            float4* orow = (float4*)((float*)out + (size_t)n * 128);
            orow[q * 2]     = make_float4(r[0], r[1], r[2], r[3]);
            orow[q * 2 + 1] = make_float4(r[4], r[5], r[6], r[7]);
        }
    }
}

template <typename OT>
__global__ __launch_bounds__(256) void k_gcn_agg(
    const __half* __restrict__ xw, const int* __restrict__ rowp,
    const int* __restrict__ esrc, const float* __restrict__ inv,
    const float* __restrict__ bias, OT* __restrict__ out, int Nn) {
    int gid = blockIdx.x * 256 + threadIdx.x;
    int n = gid >> 6, lane = gid & 63;
    if (n >= Nn) return;
    int q = lane & 15, g = lane >> 4;
    int beg = rowp[n], end = rowp[n + 1];
    float invd = inv[n];
    float acc[8] = {0.f, 0.f, 0.f, 0.f, 0.f, 0.f, 0.f, 0.f};
    for (int base = beg; base < end; base += WAVE) {
        int e = base + lane;
        bool valid = (e < end);
        int sid = valid ? esrc[e] : 0;
        float c = valid ? invd * inv[sid] : 0.f;
        gather_accum_h(xw, q, g, min(WAVE, end - base), sid, c, acc);
    }
    finish_store_q(acc, bias, out, n, q, g);
}

template <typename OT>
__global__ __launch_bounds__(256) void k_gat_agg(
    const __half* __restrict__ xw, const int* __restrict__ rowp,
    const int* __restrict__ esrc, const float* __restrict__ as_,
    const float* __restrict__ ad_, const float* __restrict__ bias,
    OT* __restrict__ out, int Nn) {
    int gid = blockIdx.x * 256 + threadIdx.x;
    int n = gid >> 6, lane = gid & 63;
    if (n >= Nn) return;
    int q = lane & 15, g = lane >> 4;
    int beg = rowp[n], end = rowp[n + 1];
    int deg = end - beg;
    float adn = ad_[n];
    float acc[8] = {0.f, 0.f, 0.f, 0.f, 0.f, 0.f, 0.f, 0.f};

    if (deg <= WAVE) {
        // fused path (deg<=64, ~all nodes): edge data loaded once, logit in reg
        bool valid = (lane < deg);
        int sid = 0;
        float v = -1e30f;
        if (valid) {
            sid = esrc[beg + lane];
            float t = as_[sid] + adn;
            v = (t > 0.f) ? t : 0.2f * t;
        }
        float m = v;
#pragma unroll
        for (int off = 32; off > 0; off >>= 1) m = fmaxf(m, __shfl_xor(m, off));
        float ex = valid ? __expf(v - m) : 0.f;
        float ssum = ex;
#pragma unroll
        for (int off = 32; off > 0; off >>= 1) ssum += __shfl_xor(ssum, off);
        float wgt = ex * (1.f / ssum);   // invalid lanes: 0
        gather_accum_h(xw, q, g, deg, sid, wgt, acc);
    } else {
        // generic two-pass path (deg>64: essentially never at E/N=16)
        float m = -1e30f, ssum = 0.f;
        for (int e = beg + lane; e < end; e += WAVE) {
            float v = as_[esrc[e]] + adn;
            v = (v > 0.f) ? v : 0.2f * v;
            float mn = fmaxf(m, v);
            ssum = ssum * __expf(m - mn) + __expf(v - mn);
            m = mn;
        }
#pragma unroll
        for (int off = 32; off > 0; off >>= 1) {
            float mo = __shfl_xor(m, off);
            float so = __shfl_xor(ssum, off);
            float mn = fmaxf(m, mo);
            ssum = ssum * __expf(m - mn) + so * __expf(mo - mn);
            m = mn;
        }
        float rden = 1.f / ssum;
        for (int base = beg; base < end; base += WAVE) {
            int e = base + lane;
            bool valid = (e < end);
            int sid = valid ? esrc[e] : 0;
            float wgt = 0.f;
            if (valid) {
                float v = as_[sid] + adn;
                v = (v > 0.f) ? v : 0.2f * v;
                wgt = __expf(v - m) * rden;
            }
            gather_accum_h(xw, q, g, min(WAVE, end - base), sid, wgt, acc);
        }
    }
    finish_store_q(acc, bias, out, n, q, g);
}

// ------------------------------- launch ------------------------------------

extern "C" void kernel_launch(void* const* d_in, const int* in_sizes, int n_in,
                              void* d_out, int out_size, void* d_ws, size_t ws_size,
                              hipStream_t stream) {
    const float* x   = (const float*)d_in[0];
    const int*   ei  = (const int*)d_in[1];
    const float* W1  = (const float*)d_in[2];
    const float* b1  = (const float*)d_in[3];
    const float* Wg1 = (const float*)d_in[4];
    const float* as1 = (const float*)d_in[5];
    const float* ad1 = (const float*)d_in[6];
    const float* bg1 = (const float*)d_in[7];
    const float* W2  = (const float*)d_in[8];
    const float* b2  = (const float*)d_in[9];
    const float* Wg2 = (const float*)d_in[10];
    const float* as2 = (const float*)d_in[11];
    const float* ad2 = (const float*)d_in[12];
    const float* bg2 = (const float*)d_in[13];
    const float* Wo  = (const float*)d_in[14];
    const float* bo  = (const float*)d_in[15];

    const int Nn = in_sizes[0] / 128;
    const int E  = in_sizes[1] / 2;
    const int Et = E + Nn;
    const int H  = 128;
    const int nbuck = (Nn + BK - 1) / BK;   // 196

    float* outH = (float*)d_out;
    float* outZ = outH + (size_t)Nn * H;

    char* p = (char*)d_ws;
    auto carve = [&](size_t bytes) {
        char* r = p;
        p += (bytes + 255) & ~(size_t)255;
        return r;
    };
    __half* bufA = (__half*)carve((size_t)Nn * H * sizeof(__half));  // xw fp16
    __half* bufB = (__half*)carve((size_t)Nn * H * sizeof(__half));  // h fp16
    __half* Wt   = (__half*)carve((size_t)73728 * sizeof(__half));   // fp16 W frags x5
    float* alS   = (float*)carve((size_t)Nn * sizeof(float));
    float* alD   = (float*)carve((size_t)Nn * sizeof(float));
    float* inv   = (float*)carve((size_t)Nn * sizeof(float));
    int*   rowp  = (int*)carve((size_t)(Nn + 1) * sizeof(int));
    int*   esrc  = (int*)carve((size_t)Et * sizeof(int));
    int2*  ebuf  = (int2*)carve((size_t)Et * sizeof(int2));
    int*   bcnt  = (int*)carve((size_t)nbuck * sizeof(int));
    int*   bbase = (int*)carve((size_t)(nbuck + 1) * sizeof(int));
    int*   bcur  = (int*)carve((size_t)nbuck * sizeof(int));
    (void)ws_size; (void)n_in; (void)out_size;

    const int aggBlocks = (Nn * WAVE + 255) / 256;   // 12500: 1 node/wave
    const int gemmB = (Nn + 63) / 64;                // 782
    const int scatB = (Et + CHUNK - 1) / CHUNK;      // 208

    // graph build (two-level bucket sort) + weight convert
    hipMemsetAsync(bcnt, 0, (size_t)nbuck * sizeof(int), stream);
    k_bhist_wcvt<<<288, 256, 0, stream>>>(ei, bcnt, E, Et, nbuck,
                                          W1, Wg1, W2, Wg2, Wo, Wt);
    k_bscan<<<1, 256, 0, stream>>>(bcnt, bbase, bcur, nbuck);
    k_bscatter<<<scatB, 256, 0, stream>>>(ei, bcur, ebuf, E, Et, nbuck);
    k_csr<<<nbuck, 256, 0, stream>>>(ebuf, bbase, rowp, inv, esrc, Nn, Et);

    // layer 1: GCN
    gemm_mfma<float, 128, __half><<<gemmB, 256, 0, stream>>>(
        x, Wt, nullptr, bufA, nullptr, nullptr, nullptr, nullptr, Nn);
    k_gcn_agg<__half><<<aggBlocks, 256, 0, stream>>>(
        bufA, rowp, esrc, inv, b1, bufB, Nn);

    // layer 2: GAT
    gemm_mfma<__half, 128, __half><<<gemmB, 256, 0, stream>>>(
        bufB, Wt + 16384, nullptr, bufA, as1, ad1, alS, alD, Nn);
    k_gat_agg<__half><<<aggBlocks, 256, 0, stream>>>(
        bufA, rowp, esrc, alS, alD, bg1, bufB, Nn);

    // layer 3: GCN
    gemm_mfma<__half, 128, __half><<<gemmB, 256, 0, stream>>>(
        bufB, Wt + 32768, nullptr, bufA, nullptr, nullptr, nullptr, nullptr, Nn);
    k_gcn_agg<__half><<<aggBlocks, 256, 0, stream>>>(
        bufA, rowp, esrc, inv, b2, bufB, Nn);

    // layer 4: GAT -> fp32 outH (required output h)
    gemm_mfma<__half, 128, __half><<<gemmB, 256, 0, stream>>>(
        bufB, Wt + 49152, nullptr, bufA, as2, ad2, alS, alD, Nn);
    k_gat_agg<float><<<aggBlocks, 256, 0, stream>>>(
        bufA, rowp, esrc, alS, alD, bg2, outH, Nn);

    // output layer: z = h @ Wo + bo
    gemm_mfma<float, 64, float><<<gemmB, 256, 0, stream>>>(
        outH, Wt + 65536, bo, outZ, nullptr, nullptr, nullptr, nullptr, Nn);
}